// Round 10
// baseline (126.069 us; speedup 1.0000x reference)
//
#include <hip/hip_runtime.h>

// SeqAdder: y[b,l], c_final[b] from a sequential per-digit MLP adder scan.
// Speculative chunked scan: the carry recurrence is contracting, so each
// chunk reconstructs its incoming carry with a WARM-step warmup from c=0.5.
// Chunk 0 starts from the exact c0=0.
// Ledger: absmax pinned at bf16 floor (1.95e-3) for WARM=64 (R1-R4) and
// WARM=48 (R8) => g <= 0.904. WARM=48 kept (R9's WARM=40 misaligned the
// warmup to a 160B offset: FETCH +23MB, net negative).
// R10 = R8 numerics + structure deltas:
//   (1) 2-way ILP: each lane runs TWO independent scans (chunks ci, ci+16
//       of its row) interleaved step-by-step. TLP is capped at 2 waves/SIMD
//       (131072 items); VALUBusy stuck ~55% => both waves co-stall on the
//       serial carry chain + load-use latency. Interleaving fills those
//       bubbles with the sibling scan at ZERO extra steps (unlike R2's
//       CHUNK=64 which paid +34% speculative work).
//   (2) bb1/b2s/b2c pinned to VGPRs via zero-instruction asm("":"+v"):
//       pre-fma read w1b(SGPR)+bb1(SGPR) = 2 scalar operands => compiler
//       emitted ~16 v_movs/step. Pin kills them. (R9's KEEP4 failed
//       differently: per-vector asm doesn't pin cross-load ordering.)
//   (3) GRAN=8 so the doubled main body stays ~14KB (I-cache, R4 lesson).

#define HIDDEN 16
constexpr int Bn = 4096;
constexpr int Ln = 4096;
constexpr int CHUNK = 128;           // steps written per scan
constexpr int WARM = 48;             // warmup steps (carry only), 64B-aligned
constexpr int NCHUNK = Ln / CHUNK;   // 32
constexpr int PAIR = NCHUNK / 2;     // 16: lane runs chunks (ci, ci+16)
constexpr int GRAN = 8;              // floats per group per scan (32B/lane)
constexpr int WG = WARM / GRAN;      // 6 warm groups
constexpr int MG = CHUNK / GRAN;     // 16 main groups

__device__ __forceinline__ float fast_exp2(float x) {
#if __has_builtin(__builtin_amdgcn_exp2f)
  return __builtin_amdgcn_exp2f(x);
#else
  return exp2f(x);
#endif
}
__device__ __forceinline__ float fast_rcp(float x) {
#if __has_builtin(__builtin_amdgcn_rcpf)
  return __builtin_amdgcn_rcpf(x);
#else
  return 1.0f / x;
#endif
}
// with z already scaled by -log2(e):  sigmoid = 1 / (1 + 2^z)
__device__ __forceinline__ float sigmoid_pre(float z) {
  return fast_rcp(1.0f + fast_exp2(z));
}

// Zero-instruction VGPR pin (forces allocation, emits nothing).
#define PIN_V(x) asm("" : "+v"(x))

// One adder step, carry-only (warmup).
#define CARRY_STEP(aV, bV, cV)                                          \
  do {                                                                  \
    float pre_[HIDDEN];                                                 \
    _Pragma("unroll") for (int j_ = 0; j_ < HIDDEN; ++j_)               \
        pre_[j_] = fmaf((aV), w1a[j_], fmaf((bV), w1b[j_], bb1[j_]));   \
    float zc0_ = b2cv, zc1_ = 0.f, zc2_ = 0.f, zc3_ = 0.f;              \
    _Pragma("unroll") for (int j_ = 0; j_ < HIDDEN; j_ += 4) {          \
      float h0_ = fmaxf(fmaf((cV), w1c[j_ + 0], pre_[j_ + 0]), 0.f);    \
      float h1_ = fmaxf(fmaf((cV), w1c[j_ + 1], pre_[j_ + 1]), 0.f);    \
      float h2_ = fmaxf(fmaf((cV), w1c[j_ + 2], pre_[j_ + 2]), 0.f);    \
      float h3_ = fmaxf(fmaf((cV), w1c[j_ + 3], pre_[j_ + 3]), 0.f);    \
      zc0_ = fmaf(h0_, w2c[j_ + 0], zc0_);                              \
      zc1_ = fmaf(h1_, w2c[j_ + 1], zc1_);                              \
      zc2_ = fmaf(h2_, w2c[j_ + 2], zc2_);                              \
      zc3_ = fmaf(h3_, w2c[j_ + 3], zc3_);                              \
    }                                                                   \
    (cV) = sigmoid_pre((zc0_ + zc1_) + (zc2_ + zc3_));                  \
  } while (0)

// One adder step, emitting the sum bit.
#define FULL_STEP(aV, bV, cV, yO)                                       \
  do {                                                                  \
    float pre_[HIDDEN];                                                 \
    _Pragma("unroll") for (int j_ = 0; j_ < HIDDEN; ++j_)               \
        pre_[j_] = fmaf((aV), w1a[j_], fmaf((bV), w1b[j_], bb1[j_]));   \
    float zc0_ = b2cv, zc1_ = 0.f, zc2_ = 0.f, zc3_ = 0.f;              \
    float zs0_ = b2sv, zs1_ = 0.f;                                      \
    _Pragma("unroll") for (int j_ = 0; j_ < HIDDEN; j_ += 4) {          \
      float h0_ = fmaxf(fmaf((cV), w1c[j_ + 0], pre_[j_ + 0]), 0.f);    \
      float h1_ = fmaxf(fmaf((cV), w1c[j_ + 1], pre_[j_ + 1]), 0.f);    \
      float h2_ = fmaxf(fmaf((cV), w1c[j_ + 2], pre_[j_ + 2]), 0.f);    \
      float h3_ = fmaxf(fmaf((cV), w1c[j_ + 3], pre_[j_ + 3]), 0.f);    \
      zc0_ = fmaf(h0_, w2c[j_ + 0], zc0_);                              \
      zc1_ = fmaf(h1_, w2c[j_ + 1], zc1_);                              \
      zc2_ = fmaf(h2_, w2c[j_ + 2], zc2_);                              \
      zc3_ = fmaf(h3_, w2c[j_ + 3], zc3_);                              \
      zs0_ = fmaf(h0_, w2s[j_ + 0], fmaf(h1_, w2s[j_ + 1], zs0_));      \
      zs1_ = fmaf(h2_, w2s[j_ + 2], fmaf(h3_, w2s[j_ + 3], zs1_));      \
    }                                                                   \
    (yO) = sigmoid_pre(zs0_ + zs1_);                                    \
    (cV) = sigmoid_pre((zc0_ + zc1_) + (zc2_ + zc3_));                  \
  } while (0)

__global__ __launch_bounds__(64) void seq_adder_kernel(
    const float* __restrict__ x1, const float* __restrict__ x2,
    const float* __restrict__ W1, const float* __restrict__ b1,
    const float* __restrict__ W2, const float* __restrict__ b2,
    float* __restrict__ out) {
  const int row = blockIdx.x * 64 + threadIdx.x;
  const int ciA = blockIdx.y;          // scan A: chunk ciA
  const int ciB = ciA + PAIR;          // scan B: chunk ciA+16 (same row)

  constexpr float NLOG2E = -1.4426950408889634f;

  // Wave-uniform weights -> SGPRs, EXCEPT bb1/b2s/b2c pinned to VGPRs so
  // every fma reads at most one scalar operand (no per-step v_movs).
  float w1a[HIDDEN], w1b[HIDDEN], w1c[HIDDEN], bb1[HIDDEN];
  float w2s[HIDDEN], w2c[HIDDEN];
#pragma unroll
  for (int j = 0; j < HIDDEN; ++j) {
    w1a[j] = W1[j];                       // W1[0, j] (multiplies a)
    w1b[j] = W1[HIDDEN + j];              // W1[1, j] (multiplies b)
    w1c[j] = W1[2 * HIDDEN + j];          // W1[2, j] (multiplies carry)
    bb1[j] = b1[j];
    PIN_V(bb1[j]);
    w2s[j] = W2[2 * j + 0] * NLOG2E;      // fold -log2(e) into layer 2
    w2c[j] = W2[2 * j + 1] * NLOG2E;
  }
  float b2sv = b2[0] * NLOG2E, b2cv = b2[1] * NLOG2E;
  PIN_V(b2sv);
  PIN_V(b2cv);

  const float* __restrict__ r1 = x1 + (size_t)row * Ln;
  const float* __restrict__ r2 = x2 + (size_t)row * Ln;
  float* __restrict__ yo = out + (size_t)row * Ln;

  const int lA = ciA * CHUNK;
  const int lB = ciB * CHUNK;
  float cA, cB;

  if (ciA == 0) {
    cA = 0.0f;   // exact initial carry for chunk 0
    cB = 0.5f;
#pragma unroll 1
    for (int g = 0; g < WG; ++g) {
      const int lb = lB - WARM + g * GRAN;
      float4 a4[2], b4[2];
      a4[0] = *reinterpret_cast<const float4*>(r1 + lb);
      a4[1] = *reinterpret_cast<const float4*>(r1 + lb + 4);
      b4[0] = *reinterpret_cast<const float4*>(r2 + lb);
      b4[1] = *reinterpret_cast<const float4*>(r2 + lb + 4);
      const float* af = reinterpret_cast<const float*>(a4);
      const float* bf = reinterpret_cast<const float*>(b4);
#pragma unroll
      for (int u = 0; u < GRAN; ++u) CARRY_STEP(af[u], bf[u], cB);
    }
  } else {
    cA = 0.5f;
    cB = 0.5f;
#pragma unroll 1
    for (int g = 0; g < WG; ++g) {
      const int lbA = lA - WARM + g * GRAN;
      const int lbB = lB - WARM + g * GRAN;
      float4 aA[2], bA[2], aB[2], bB[2];
      aA[0] = *reinterpret_cast<const float4*>(r1 + lbA);
      aA[1] = *reinterpret_cast<const float4*>(r1 + lbA + 4);
      bA[0] = *reinterpret_cast<const float4*>(r2 + lbA);
      bA[1] = *reinterpret_cast<const float4*>(r2 + lbA + 4);
      aB[0] = *reinterpret_cast<const float4*>(r1 + lbB);
      aB[1] = *reinterpret_cast<const float4*>(r1 + lbB + 4);
      bB[0] = *reinterpret_cast<const float4*>(r2 + lbB);
      bB[1] = *reinterpret_cast<const float4*>(r2 + lbB + 4);
      const float* afA = reinterpret_cast<const float*>(aA);
      const float* bfA = reinterpret_cast<const float*>(bA);
      const float* afB = reinterpret_cast<const float*>(aB);
      const float* bfB = reinterpret_cast<const float*>(bB);
#pragma unroll
      for (int u = 0; u < GRAN; ++u) {
        CARRY_STEP(afA[u], bfA[u], cA);   // independent chains:
        CARRY_STEP(afB[u], bfB[u], cB);   // scheduler interleaves
      }
    }
  }

  // Main: both scans emit sum bits, interleaved step-by-step.
#pragma unroll 1
  for (int g = 0; g < MG; ++g) {
    const int lbA = lA + g * GRAN;
    const int lbB = lB + g * GRAN;
    float4 aA[2], bA[2], aB[2], bB[2], yA[2], yB[2];
    aA[0] = *reinterpret_cast<const float4*>(r1 + lbA);
    aA[1] = *reinterpret_cast<const float4*>(r1 + lbA + 4);
    bA[0] = *reinterpret_cast<const float4*>(r2 + lbA);
    bA[1] = *reinterpret_cast<const float4*>(r2 + lbA + 4);
    aB[0] = *reinterpret_cast<const float4*>(r1 + lbB);
    aB[1] = *reinterpret_cast<const float4*>(r1 + lbB + 4);
    bB[0] = *reinterpret_cast<const float4*>(r2 + lbB);
    bB[1] = *reinterpret_cast<const float4*>(r2 + lbB + 4);
    const float* afA = reinterpret_cast<const float*>(aA);
    const float* bfA = reinterpret_cast<const float*>(bA);
    const float* afB = reinterpret_cast<const float*>(aB);
    const float* bfB = reinterpret_cast<const float*>(bB);
    float* yfA = reinterpret_cast<float*>(yA);
    float* yfB = reinterpret_cast<float*>(yB);
#pragma unroll
    for (int u = 0; u < GRAN; ++u) {
      FULL_STEP(afA[u], bfA[u], cA, yfA[u]);
      FULL_STEP(afB[u], bfB[u], cB, yfB[u]);
    }
    *reinterpret_cast<float4*>(yo + lbA) = yA[0];
    *reinterpret_cast<float4*>(yo + lbA + 4) = yA[1];
    *reinterpret_cast<float4*>(yo + lbB) = yB[0];
    *reinterpret_cast<float4*>(yo + lbB + 4) = yB[1];
  }

  // Scan B of the last pair owns the final carry output.
  if (ciA == PAIR - 1) {
    out[(size_t)Bn * Ln + row] = cB;
  }
}

extern "C" void kernel_launch(void* const* d_in, const int* in_sizes, int n_in,
                              void* d_out, int out_size, void* d_ws,
                              size_t ws_size, hipStream_t stream) {
  const float* x1 = (const float*)d_in[0];
  const float* x2 = (const float*)d_in[1];
  const float* W1 = (const float*)d_in[2];
  const float* b1 = (const float*)d_in[3];
  const float* W2 = (const float*)d_in[4];
  const float* b2 = (const float*)d_in[5];
  float* out = (float*)d_out;

  dim3 grid(Bn / 64, PAIR);
  seq_adder_kernel<<<grid, 64, 0, stream>>>(x1, x2, W1, b1, W2, b2, out);
}